// Round 4
// baseline (1908.928 us; speedup 1.0000x reference)
//
#include <hip/hip_runtime.h>
#include <hip/hip_bf16.h>

typedef __bf16 bf16;
typedef __bf16 bf16x8 __attribute__((ext_vector_type(8)));
typedef float f32x4 __attribute__((ext_vector_type(4)));
typedef unsigned int u32;

#define D_    2048
#define NSEQ  4096
#define BATCH 2
#define BS_   256
#define TCH   16
#define MROWS 8192  // BATCH*NSEQ

__device__ __forceinline__ void gload16(const bf16* g, bf16* l) {
  __builtin_amdgcn_global_load_lds(
      (const __attribute__((address_space(1))) u32*)g,
      (__attribute__((address_space(3))) u32*)l, 16, 0, 0);
}

struct SmemTiles {
  alignas(16) bf16 As[128 * 32];
  alignas(16) bf16 Bs[128 * 32];
};

// Accumulate a 128x128 C tile: C += A[128,K] * B[128,K]^T
// A row-major (lda, K contiguous), B row-major (ldb, K contiguous)
__device__ __forceinline__ void gemm_core(SmemTiles& sm, const bf16* A, int lda,
                                          const bf16* B, int ldb, int K,
                                          f32x4 acc[4][4]) {
  const int tid = threadIdx.x;
  const int lane = tid & 63;
  const int wave = tid >> 6;
  const int wr = wave >> 1, wc = wave & 1;
  const int l15 = lane & 15, kl = lane >> 4;
  const bf16* Ar = sm.As + (wr * 64 + l15) * 32 + kl * 8;
  const bf16* Br = sm.Bs + (wc * 64 + l15) * 32 + kl * 8;

  for (int k0 = 0; k0 < K; k0 += 32) {
#pragma unroll
    for (int it = 0; it < 2; ++it) {
      int c = it * 256 + tid;      // 16B chunk index, 512 chunks per tile
      int r = c >> 2;              // 4 chunks per 32-elem row
      int co = (c & 3) << 3;
      gload16(A + r * lda + k0 + co, sm.As + c * 8);
      gload16(B + r * ldb + k0 + co, sm.Bs + c * 8);
    }
    __syncthreads();
    bf16x8 a[4], b[4];
#pragma unroll
    for (int m = 0; m < 4; ++m) a[m] = *(const bf16x8*)(Ar + m * 16 * 32);
#pragma unroll
    for (int n = 0; n < 4; ++n) b[n] = *(const bf16x8*)(Br + n * 16 * 32);
#pragma unroll
    for (int m = 0; m < 4; ++m)
#pragma unroll
      for (int n = 0; n < 4; ++n)
        acc[m][n] = __builtin_amdgcn_mfma_f32_16x16x32_bf16(a[m], b[n], acc[m][n], 0, 0, 0);
    __syncthreads();
  }
}

#define EPILOGUE_VARS                              \
  const int lane = threadIdx.x & 63;               \
  const int wave = threadIdx.x >> 6;               \
  const int wr = wave >> 1, wc = wave & 1;         \
  const int l15 = lane & 15, kl = lane >> 4;

// ---------------- elementwise kernels ----------------

__global__ __launch_bounds__(256) void k_f2b(const float* __restrict__ in,
                                             bf16* __restrict__ out) {
  int i = (blockIdx.x * 256 + threadIdx.x) * 8;
  float4 a = *(const float4*)(in + i);
  float4 b = *(const float4*)(in + i + 4);
  bf16x8 o;
  o[0] = (bf16)a.x; o[1] = (bf16)a.y; o[2] = (bf16)a.z; o[3] = (bf16)a.w;
  o[4] = (bf16)b.x; o[5] = (bf16)b.y; o[6] = (bf16)b.z; o[7] = (bf16)b.w;
  *(bf16x8*)(out + i) = o;
}

__global__ __launch_bounds__(256) void k_rms(const float* __restrict__ x,
                                             bf16* __restrict__ xn) {
  const int row = blockIdx.x;
  const int tid = threadIdx.x;
  const float* xr = x + (size_t)row * D_;
  float4 a = *(const float4*)(xr + tid * 8);
  float4 b = *(const float4*)(xr + tid * 8 + 4);
  float ss = a.x * a.x + a.y * a.y + a.z * a.z + a.w * a.w +
             b.x * b.x + b.y * b.y + b.z * b.z + b.w * b.w;
#pragma unroll
  for (int o = 32; o > 0; o >>= 1) ss += __shfl_xor(ss, o, 64);
  __shared__ float red[4];
  if ((tid & 63) == 0) red[tid >> 6] = ss;
  __syncthreads();
  float tot = red[0] + red[1] + red[2] + red[3];
  float sc = rsqrtf(tot * (1.f / D_) + 1.1920928955078125e-07f);
  bf16x8 o;
  o[0] = (bf16)(a.x * sc); o[1] = (bf16)(a.y * sc);
  o[2] = (bf16)(a.z * sc); o[3] = (bf16)(a.w * sc);
  o[4] = (bf16)(b.x * sc); o[5] = (bf16)(b.y * sc);
  o[6] = (bf16)(b.z * sc); o[7] = (bf16)(b.w * sc);
  *(bf16x8*)(xn + (size_t)row * D_ + tid * 8) = o;
}

// ---------------- GEMM kernels ----------------

// C = act(xn @ W^T); SMODE bit0: store normal [8192,2048], bit1: store transposed [B][D][N]
template <int ACT, int SMODE>
__global__ __launch_bounds__(256) void k_proj(const bf16* __restrict__ xn,
                                              const bf16* __restrict__ W,
                                              bf16* __restrict__ Cn,
                                              bf16* __restrict__ Ct) {
  __shared__ SmemTiles sm;
  const int row0 = blockIdx.y * 128, col0 = blockIdx.x * 128;
  f32x4 acc[4][4] = {};
  gemm_core(sm, xn + (size_t)row0 * D_, D_, W + (size_t)col0 * D_, D_, D_, acc);
  EPILOGUE_VARS
#pragma unroll
  for (int m = 0; m < 4; ++m)
#pragma unroll
    for (int n = 0; n < 4; ++n)
#pragma unroll
      for (int j = 0; j < 4; ++j) {
        int r = row0 + wr * 64 + m * 16 + kl * 4 + j;
        int c = col0 + wc * 64 + n * 16 + l15;
        float v = acc[m][n][j];
        if (ACT == 1) v = v / (1.f + __expf(-v));        // silu
        if (ACT == 2) v = 1.f / (1.f + __expf(-v));      // sigmoid
        bf16 ob = (bf16)v;
        if (SMODE & 1) Cn[(size_t)r * D_ + c] = ob;
        if (SMODE & 2)
          Ct[((size_t)(r >> 12) * D_ + c) * NSEQ + (r & (NSEQ - 1))] = ob;
      }
}

// s[z] = tril(q_t k_t^T), z = b*16 + t
__global__ __launch_bounds__(256) void k_scores(const bf16* __restrict__ q,
                                                const bf16* __restrict__ k,
                                                bf16* __restrict__ s) {
  __shared__ SmemTiles sm;
  const int z = blockIdx.z, b = z >> 4, t = z & 15;
  const int row0 = blockIdx.y * 128, col0 = blockIdx.x * 128;
  f32x4 acc[4][4] = {};
  if (row0 + 127 >= col0)  // fully-masked tile: skip compute, still store zeros
    gemm_core(sm, q + (size_t)(b * NSEQ + t * BS_ + row0) * D_, D_,
                  k + (size_t)(b * NSEQ + t * BS_ + col0) * D_, D_, D_, acc);
  EPILOGUE_VARS
  bf16* sp = s + (size_t)z * BS_ * BS_;
#pragma unroll
  for (int m = 0; m < 4; ++m)
#pragma unroll
    for (int n = 0; n < 4; ++n)
#pragma unroll
      for (int j = 0; j < 4; ++j) {
        int i = row0 + wr * 64 + m * 16 + kl * 4 + j;
        int jc = col0 + wc * 64 + n * 16 + l15;
        float v = (i >= jc) ? acc[m][n][j] : 0.f;
        sp[i * BS_ + jc] = (bf16)v;
      }
}

// og[chunk rows] = s @ v   (intra-chunk part, all chunks parallel)
__global__ __launch_bounds__(256) void k_ointra(const bf16* __restrict__ s,
                                                const bf16* __restrict__ vT,
                                                bf16* __restrict__ og) {
  __shared__ SmemTiles sm;
  const int z = blockIdx.z, b = z >> 4, t = z & 15;
  const int row0 = blockIdx.y * 128, col0 = blockIdx.x * 128;
  f32x4 acc[4][4] = {};
  gemm_core(sm, s + (size_t)z * BS_ * BS_ + row0 * BS_, BS_,
                vT + (size_t)b * D_ * NSEQ + (size_t)col0 * NSEQ + t * BS_, NSEQ,
                BS_, acc);
  EPILOGUE_VARS
#pragma unroll
  for (int m = 0; m < 4; ++m)
#pragma unroll
    for (int n = 0; n < 4; ++n)
#pragma unroll
      for (int j = 0; j < 4; ++j) {
        int i = row0 + wr * 64 + m * 16 + kl * 4 + j;
        int c = col0 + wc * 64 + n * 16 + l15;
        og[(size_t)(b * NSEQ + t * BS_ + i) * D_ + c] = (bf16)acc[m][n][j];
      }
}

// og = (og + q_t @ kvT^T) * g   for chunk t (Kin==0 for t==0: just gate)
__global__ __launch_bounds__(256) void k_ointer(const bf16* __restrict__ q,
                                                const bf16* __restrict__ kvb,
                                                const bf16* __restrict__ g,
                                                bf16* __restrict__ og, int t,
                                                int Kin) {
  __shared__ SmemTiles sm;
  const int b = blockIdx.z;
  const int row0 = blockIdx.y * 128, col0 = blockIdx.x * 128;
  f32x4 acc[4][4] = {};
  gemm_core(sm, q + (size_t)(b * NSEQ + t * BS_ + row0) * D_, D_,
                kvb + (size_t)b * D_ * D_ + (size_t)col0 * D_, D_, Kin, acc);
  EPILOGUE_VARS
#pragma unroll
  for (int m = 0; m < 4; ++m)
#pragma unroll
    for (int n = 0; n < 4; ++n)
#pragma unroll
      for (int j = 0; j < 4; ++j) {
        int i = row0 + wr * 64 + m * 16 + kl * 4 + j;
        int c = col0 + wc * 64 + n * 16 + l15;
        size_t idx = (size_t)(b * NSEQ + t * BS_ + i) * D_ + c;
        float v = ((float)og[idx] + acc[m][n][j]) * (float)g[idx];
        og[idx] = (bf16)v;
      }
}

// kvT[b][e][d] += sum_j v[j][e] k[j][d]  (fp32 master + bf16 mirror)
__global__ __launch_bounds__(256) void k_update(const bf16* __restrict__ vT,
                                                const bf16* __restrict__ kT,
                                                float* __restrict__ kvf,
                                                bf16* __restrict__ kvb, int t) {
  __shared__ SmemTiles sm;
  const int b = blockIdx.z;
  const int row0 = blockIdx.y * 128, col0 = blockIdx.x * 128;  // row=e, col=d
  f32x4 acc[4][4] = {};
  gemm_core(sm, vT + (size_t)b * D_ * NSEQ + (size_t)row0 * NSEQ + t * BS_, NSEQ,
                kT + (size_t)b * D_ * NSEQ + (size_t)col0 * NSEQ + t * BS_, NSEQ,
                BS_, acc);
  EPILOGUE_VARS
#pragma unroll
  for (int m = 0; m < 4; ++m)
#pragma unroll
    for (int n = 0; n < 4; ++n)
#pragma unroll
      for (int j = 0; j < 4; ++j) {
        int e = row0 + wr * 64 + m * 16 + kl * 4 + j;
        int d = col0 + wc * 64 + n * 16 + l15;
        size_t idx = (size_t)b * D_ * D_ + (size_t)e * D_ + d;
        float v = kvf[idx] + acc[m][n][j];
        kvf[idx] = v;
        kvb[idx] = (bf16)v;
      }
}

// out = og @ Wp^T (fp32 store)
__global__ __launch_bounds__(256) void k_final(const bf16* __restrict__ og,
                                               const bf16* __restrict__ Wp,
                                               float* __restrict__ out) {
  __shared__ SmemTiles sm;
  const int row0 = blockIdx.y * 128, col0 = blockIdx.x * 128;
  f32x4 acc[4][4] = {};
  gemm_core(sm, og + (size_t)row0 * D_, D_, Wp + (size_t)col0 * D_, D_, D_, acc);
  EPILOGUE_VARS
#pragma unroll
  for (int m = 0; m < 4; ++m)
#pragma unroll
    for (int n = 0; n < 4; ++n)
#pragma unroll
      for (int j = 0; j < 4; ++j) {
        int r = row0 + wr * 64 + m * 16 + kl * 4 + j;
        int c = col0 + wc * 64 + n * 16 + l15;
        out[(size_t)r * D_ + c] = acc[m][n][j];
      }
}

// ---------------- host launch ----------------
//
// Workspace budget (crash fix): previous plan used 284 MiB of d_ws without
// checking ws_size -> likely OOB -> GPU memory fault. New plan: 156 MiB.
//   - q and g live inside d_out (64 MiB = exactly 2x 32 MiB bf16 buffers);
//     both are dead before k_final overwrites d_out with the fp32 result.
//   - single 8 MiB weight buffer, converted just-in-time (weight use is
//     strictly sequential in stream order).
//   - fp32 KV master shares the k-normal buffer (k dead after k_scores,
//     kvf memset enqueued after it in stream order).

extern "C" void kernel_launch(void* const* d_in, const int* in_sizes, int n_in,
                              void* d_out, int out_size, void* d_ws, size_t ws_size,
                              hipStream_t stream) {
  (void)in_sizes; (void)n_in; (void)out_size; (void)ws_size;
  const float* x  = (const float*)d_in[0];
  const float* Wq = (const float*)d_in[1];
  const float* Wk = (const float*)d_in[2];
  const float* Wv = (const float*)d_in[3];
  const float* Wg = (const float*)d_in[4];
  const float* Wp = (const float*)d_in[5];
  float* out = (float*)d_out;

  char* p = (char*)d_ws;
  auto take = [&](size_t bytes) {
    char* r = p;
    p += (bytes + 255) & ~(size_t)255;
    return r;
  };
  const size_t MD2 = (size_t)MROWS * D_ * 2;   // 32 MiB
  const size_t W2  = (size_t)D_ * D_ * 2;      // 8 MiB

  bf16* xn  = (bf16*)take(MD2);                        // reused as og
  bf16* kT  = (bf16*)take(MD2);
  bf16* vT  = (bf16*)take(MD2);
  char* kshare = take((size_t)BATCH * D_ * D_ * 4);    // 32 MiB: k, then kvf
  bf16*  k   = (bf16*)kshare;                          // [8192,2048] bf16 (scores only)
  float* kvf = (float*)kshare;                         // [B,2048,2048] fp32 (chunk loop)
  bf16* kvb = (bf16*)take((size_t)BATCH * D_ * D_ * 2);
  bf16* s   = (bf16*)take((size_t)BATCH * TCH * BS_ * BS_ * 2);
  bf16* Wb  = (bf16*)take(W2);                         // shared weight buffer
  bf16* og = xn;

  // q and g live in d_out (64 MiB fp32 = 2 x 32 MiB bf16); overwritten by k_final
  bf16* q = (bf16*)d_out;
  bf16* g = (bf16*)d_out + (size_t)MROWS * D_;

  const int WB = (D_ * D_) / 2048;  // 2048 blocks per weight convert
  dim3 gp(D_ / 128, MROWS / 128);   // (16, 64)

  k_rms<<<MROWS, 256, 0, stream>>>(x, xn);

  k_f2b<<<WB, 256, 0, stream>>>(Wq, Wb);
  k_proj<1, 1><<<gp, 256, 0, stream>>>(xn, Wb, q, (bf16*)nullptr);
  k_f2b<<<WB, 256, 0, stream>>>(Wk, Wb);
  k_proj<1, 3><<<gp, 256, 0, stream>>>(xn, Wb, k, kT);
  k_f2b<<<WB, 256, 0, stream>>>(Wv, Wb);
  k_proj<1, 2><<<gp, 256, 0, stream>>>(xn, Wb, (bf16*)nullptr, vT);
  k_f2b<<<WB, 256, 0, stream>>>(Wg, Wb);
  k_proj<2, 1><<<gp, 256, 0, stream>>>(xn, Wb, g, (bf16*)nullptr);

  k_scores<<<dim3(2, 2, BATCH * TCH), 256, 0, stream>>>(q, k, s);
  k_ointra<<<dim3(D_ / 128, 2, BATCH * TCH), 256, 0, stream>>>(s, vT, og);

  // k is dead now; its memory becomes the fp32 KV master
  hipMemsetAsync(kvf, 0, (size_t)BATCH * D_ * D_ * 4, stream);
  hipMemsetAsync(kvb, 0, (size_t)BATCH * D_ * D_ * 2, stream);

  for (int t = 0; t < TCH; ++t) {
    k_ointer<<<dim3(D_ / 128, 2, BATCH), 256, 0, stream>>>(q, kvb, g, og, t,
                                                           t ? D_ : 0);
    if (t < TCH - 1)
      k_update<<<dim3(D_ / 128, D_ / 128, BATCH), 256, 0, stream>>>(vT, kT, kvf,
                                                                    kvb, t);
  }

  k_f2b<<<WB, 256, 0, stream>>>(Wp, Wb);
  k_final<<<dim3(D_ / 128, MROWS / 128), 256, 0, stream>>>(og, Wb, out);
}

// Round 5
// 986.300 us; speedup vs baseline: 1.9354x; 1.9354x over previous
//
#include <hip/hip_runtime.h>
#include <hip/hip_bf16.h>

typedef __bf16 bf16;
typedef __bf16 bf16x8 __attribute__((ext_vector_type(8)));
typedef float f32x4 __attribute__((ext_vector_type(4)));
typedef unsigned int u32;

#define D_    2048
#define NSEQ  4096
#define BATCH 2
#define CH    1024   // recurrence chunk (math is chunk-size invariant)
#define TC    4      // chunks per batch
#define MROWS 8192   // BATCH*NSEQ

__device__ __forceinline__ void gload16(const bf16* g, bf16* l) {
  __builtin_amdgcn_global_load_lds(
      (const __attribute__((address_space(1))) u32*)g,
      (__attribute__((address_space(3))) u32*)l, 16, 0, 0);
}

struct SmemTiles {
  alignas(16) bf16 As[128 * 32];
  alignas(16) bf16 Bs[128 * 32];
};

// Accumulate a 128x128 C tile: C += A[128,K] * B[128,K]^T
// A row-major (lda, K contiguous), B row-major (ldb, K contiguous)
__device__ __forceinline__ void gemm_core(SmemTiles& sm, const bf16* A, int lda,
                                          const bf16* B, int ldb, int K,
                                          f32x4 acc[4][4]) {
  const int tid = threadIdx.x;
  const int lane = tid & 63;
  const int wave = tid >> 6;
  const int wr = wave >> 1, wc = wave & 1;
  const int l15 = lane & 15, kl = lane >> 4;
  const bf16* Ar = sm.As + (wr * 64 + l15) * 32 + kl * 8;
  const bf16* Br = sm.Bs + (wc * 64 + l15) * 32 + kl * 8;

  for (int k0 = 0; k0 < K; k0 += 32) {
#pragma unroll
    for (int it = 0; it < 2; ++it) {
      int c = it * 256 + tid;      // 16B chunk index, 512 chunks per tile
      int r = c >> 2;              // 4 chunks per 32-elem row
      int co = (c & 3) << 3;
      gload16(A + r * lda + k0 + co, sm.As + c * 8);
      gload16(B + r * ldb + k0 + co, sm.Bs + c * 8);
    }
    __syncthreads();
    bf16x8 a[4], b[4];
#pragma unroll
    for (int m = 0; m < 4; ++m) a[m] = *(const bf16x8*)(Ar + m * 16 * 32);
#pragma unroll
    for (int n = 0; n < 4; ++n) b[n] = *(const bf16x8*)(Br + n * 16 * 32);
#pragma unroll
    for (int m = 0; m < 4; ++m)
#pragma unroll
      for (int n = 0; n < 4; ++n)
        acc[m][n] = __builtin_amdgcn_mfma_f32_16x16x32_bf16(a[m], b[n], acc[m][n], 0, 0, 0);
    __syncthreads();
  }
}

#define EPILOGUE_VARS                              \
  const int lane = threadIdx.x & 63;               \
  const int wave = threadIdx.x >> 6;               \
  const int wr = wave >> 1, wc = wave & 1;         \
  const int l15 = lane & 15, kl = lane >> 4;

// ---------------- elementwise kernels ----------------

__global__ __launch_bounds__(256) void k_f2b(const float* __restrict__ in,
                                             bf16* __restrict__ out) {
  int i = (blockIdx.x * 256 + threadIdx.x) * 8;
  float4 a = *(const float4*)(in + i);
  float4 b = *(const float4*)(in + i + 4);
  bf16x8 o;
  o[0] = (bf16)a.x; o[1] = (bf16)a.y; o[2] = (bf16)a.z; o[3] = (bf16)a.w;
  o[4] = (bf16)b.x; o[5] = (bf16)b.y; o[6] = (bf16)b.z; o[7] = (bf16)b.w;
  *(bf16x8*)(out + i) = o;
}

__global__ __launch_bounds__(256) void k_rms(const float* __restrict__ x,
                                             bf16* __restrict__ xn) {
  const int row = blockIdx.x;
  const int tid = threadIdx.x;
  const float* xr = x + (size_t)row * D_;
  float4 a = *(const float4*)(xr + tid * 8);
  float4 b = *(const float4*)(xr + tid * 8 + 4);
  float ss = a.x * a.x + a.y * a.y + a.z * a.z + a.w * a.w +
             b.x * b.x + b.y * b.y + b.z * b.z + b.w * b.w;
#pragma unroll
  for (int o = 32; o > 0; o >>= 1) ss += __shfl_xor(ss, o, 64);
  __shared__ float red[4];
  if ((tid & 63) == 0) red[tid >> 6] = ss;
  __syncthreads();
  float tot = red[0] + red[1] + red[2] + red[3];
  float sc = rsqrtf(tot * (1.f / D_) + 1.1920928955078125e-07f);
  bf16x8 o;
  o[0] = (bf16)(a.x * sc); o[1] = (bf16)(a.y * sc);
  o[2] = (bf16)(a.z * sc); o[3] = (bf16)(a.w * sc);
  o[4] = (bf16)(b.x * sc); o[5] = (bf16)(b.y * sc);
  o[6] = (bf16)(b.z * sc); o[7] = (bf16)(b.w * sc);
  *(bf16x8*)(xn + (size_t)row * D_ + tid * 8) = o;
}

// ---------------- GEMM kernels ----------------

// C = act(xn @ W^T); SMODE bit0: store normal [8192,2048], bit1: store transposed [B][D][N]
template <int ACT, int SMODE>
__global__ __launch_bounds__(256) void k_proj(const bf16* __restrict__ xn,
                                              const bf16* __restrict__ W,
                                              bf16* __restrict__ Cn,
                                              bf16* __restrict__ Ct) {
  __shared__ SmemTiles sm;
  const int row0 = blockIdx.y * 128, col0 = blockIdx.x * 128;
  f32x4 acc[4][4] = {};
  gemm_core(sm, xn + (size_t)row0 * D_, D_, W + (size_t)col0 * D_, D_, D_, acc);
  EPILOGUE_VARS
#pragma unroll
  for (int m = 0; m < 4; ++m)
#pragma unroll
    for (int n = 0; n < 4; ++n)
#pragma unroll
      for (int j = 0; j < 4; ++j) {
        int r = row0 + wr * 64 + m * 16 + kl * 4 + j;
        int c = col0 + wc * 64 + n * 16 + l15;
        float v = acc[m][n][j];
        if (ACT == 1) v = v / (1.f + __expf(-v));        // silu
        if (ACT == 2) v = 1.f / (1.f + __expf(-v));      // sigmoid
        bf16 ob = (bf16)v;
        if (SMODE & 1) Cn[(size_t)r * D_ + c] = ob;
        if (SMODE & 2)
          Ct[((size_t)(r >> 12) * D_ + c) * NSEQ + (r & (NSEQ - 1))] = ob;
      }
}

// s[z] = tril(q_t k_t^T), z = b*TC + t, chunk CH=1024.
// Strictly-upper 128-tiles are skipped entirely (never stored, never read).
__global__ __launch_bounds__(256) void k_scores(const bf16* __restrict__ q,
                                                const bf16* __restrict__ k,
                                                bf16* __restrict__ s) {
  const int z = blockIdx.z, b = z >> 2, t = z & 3;
  const int row0 = blockIdx.y * 128, col0 = blockIdx.x * 128;
  if (col0 > row0) return;  // strictly upper tile
  __shared__ SmemTiles sm;
  f32x4 acc[4][4] = {};
  gemm_core(sm, q + (size_t)(b * NSEQ + t * CH + row0) * D_, D_,
                k + (size_t)(b * NSEQ + t * CH + col0) * D_, D_, D_, acc);
  EPILOGUE_VARS
  bf16* sp = s + (size_t)z * CH * CH;
#pragma unroll
  for (int m = 0; m < 4; ++m)
#pragma unroll
    for (int n = 0; n < 4; ++n)
#pragma unroll
      for (int j = 0; j < 4; ++j) {
        int i = row0 + wr * 64 + m * 16 + kl * 4 + j;
        int jc = col0 + wc * 64 + n * 16 + l15;
        float v = (i >= jc) ? acc[m][n][j] : 0.f;
        sp[(size_t)i * CH + jc] = (bf16)v;
      }
}

// og[chunk rows] = s @ v  (intra-chunk, all chunks parallel).
// K trimmed to the lower-triangular extent of this row block.
__global__ __launch_bounds__(256) void k_ointra(const bf16* __restrict__ s,
                                                const bf16* __restrict__ vT,
                                                bf16* __restrict__ og) {
  __shared__ SmemTiles sm;
  const int z = blockIdx.z, b = z >> 2, t = z & 3;
  const int row0 = blockIdx.y * 128, col0 = blockIdx.x * 128;
  const int K = row0 + 128;  // only s-cols <= row are nonzero/valid
  f32x4 acc[4][4] = {};
  gemm_core(sm, s + (size_t)z * CH * CH + (size_t)row0 * CH, CH,
                vT + (size_t)b * D_ * NSEQ + (size_t)col0 * NSEQ + t * CH, NSEQ,
                K, acc);
  EPILOGUE_VARS
#pragma unroll
  for (int m = 0; m < 4; ++m)
#pragma unroll
    for (int n = 0; n < 4; ++n)
#pragma unroll
      for (int j = 0; j < 4; ++j) {
        int i = row0 + wr * 64 + m * 16 + kl * 4 + j;
        int c = col0 + wc * 64 + n * 16 + l15;
        og[(size_t)(b * NSEQ + t * CH + i) * D_ + c] = (bf16)acc[m][n][j];
      }
}

// og = (og + q_t @ kvT^T) * g   for chunk t (Kin==0 for t==0: just gate)
__global__ __launch_bounds__(256) void k_ointer(const bf16* __restrict__ q,
                                                const bf16* __restrict__ kvb,
                                                const bf16* __restrict__ g,
                                                bf16* __restrict__ og, int t,
                                                int Kin) {
  __shared__ SmemTiles sm;
  const int b = blockIdx.z;
  const int row0 = blockIdx.y * 128, col0 = blockIdx.x * 128;
  f32x4 acc[4][4] = {};
  gemm_core(sm, q + (size_t)(b * NSEQ + t * CH + row0) * D_, D_,
                kvb + (size_t)b * D_ * D_ + (size_t)col0 * D_, D_, Kin, acc);
  EPILOGUE_VARS
#pragma unroll
  for (int m = 0; m < 4; ++m)
#pragma unroll
    for (int n = 0; n < 4; ++n)
#pragma unroll
      for (int j = 0; j < 4; ++j) {
        int i = row0 + wr * 64 + m * 16 + kl * 4 + j;
        int c = col0 + wc * 64 + n * 16 + l15;
        size_t idx = (size_t)(b * NSEQ + t * CH + i) * D_ + c;
        float v = ((float)og[idx] + acc[m][n][j]) * (float)g[idx];
        og[idx] = (bf16)v;
      }
}

// kvT[b][e][d] += sum_{j in chunk t} v[j][e] k[j][d]  (fp32 master + bf16 mirror)
__global__ __launch_bounds__(256) void k_update(const bf16* __restrict__ vT,
                                                const bf16* __restrict__ kT,
                                                float* __restrict__ kvf,
                                                bf16* __restrict__ kvb, int t) {
  __shared__ SmemTiles sm;
  const int b = blockIdx.z;
  const int row0 = blockIdx.y * 128, col0 = blockIdx.x * 128;  // row=e, col=d
  f32x4 acc[4][4] = {};
  gemm_core(sm, vT + (size_t)b * D_ * NSEQ + (size_t)row0 * NSEQ + t * CH, NSEQ,
                kT + (size_t)b * D_ * NSEQ + (size_t)col0 * NSEQ + t * CH, NSEQ,
                CH, acc);
  EPILOGUE_VARS
#pragma unroll
  for (int m = 0; m < 4; ++m)
#pragma unroll
    for (int n = 0; n < 4; ++n)
#pragma unroll
      for (int j = 0; j < 4; ++j) {
        int e = row0 + wr * 64 + m * 16 + kl * 4 + j;
        int d = col0 + wc * 64 + n * 16 + l15;
        size_t idx = (size_t)b * D_ * D_ + (size_t)e * D_ + d;
        float v = kvf[idx] + acc[m][n][j];
        kvf[idx] = v;
        kvb[idx] = (bf16)v;
      }
}

// out = og @ Wp^T (fp32 store)
__global__ __launch_bounds__(256) void k_final(const bf16* __restrict__ og,
                                               const bf16* __restrict__ Wp,
                                               float* __restrict__ out) {
  __shared__ SmemTiles sm;
  const int row0 = blockIdx.y * 128, col0 = blockIdx.x * 128;
  f32x4 acc[4][4] = {};
  gemm_core(sm, og + (size_t)row0 * D_, D_, Wp + (size_t)col0 * D_, D_, D_, acc);
  EPILOGUE_VARS
#pragma unroll
  for (int m = 0; m < 4; ++m)
#pragma unroll
    for (int n = 0; n < 4; ++n)
#pragma unroll
      for (int j = 0; j < 4; ++j) {
        int r = row0 + wr * 64 + m * 16 + kl * 4 + j;
        int c = col0 + wc * 64 + n * 16 + l15;
        out[(size_t)r * D_ + c] = acc[m][n][j];
      }
}

// ---------------- host launch ----------------
//
// Workspace plan (153 MiB, <= proven-working 156 MiB):
//   xn/og 32 | kT 32 | vT 32 | {k -> kvf} 32 | {s -> kvb} 16.78 | Wb 8
//   - q, g live inside d_out (64 MiB = 2x 32 MiB bf16); both dead before
//     k_final overwrites d_out.
//   - k (scores only) shares with fp32 KV master (memset after scores).
//   - s (intra only) shares with bf16 KV mirror (memset after ointra).
// Recurrence re-chunked at CH=1024 (math identical to BS=256 reference up to
// fp reordering): sequential section 31 launches/1.26 GB state traffic ->
// 7 launches/252 MB.

extern "C" void kernel_launch(void* const* d_in, const int* in_sizes, int n_in,
                              void* d_out, int out_size, void* d_ws, size_t ws_size,
                              hipStream_t stream) {
  (void)in_sizes; (void)n_in; (void)out_size; (void)ws_size;
  const float* x  = (const float*)d_in[0];
  const float* Wq = (const float*)d_in[1];
  const float* Wk = (const float*)d_in[2];
  const float* Wv = (const float*)d_in[3];
  const float* Wg = (const float*)d_in[4];
  const float* Wp = (const float*)d_in[5];
  float* out = (float*)d_out;

  char* p = (char*)d_ws;
  auto take = [&](size_t bytes) {
    char* r = p;
    p += (bytes + 255) & ~(size_t)255;
    return r;
  };
  const size_t MD2 = (size_t)MROWS * D_ * 2;   // 32 MiB
  const size_t W2  = (size_t)D_ * D_ * 2;      // 8 MiB

  bf16* xn  = (bf16*)take(MD2);                        // reused as og
  bf16* kT  = (bf16*)take(MD2);
  bf16* vT  = (bf16*)take(MD2);
  char* kshare = take((size_t)BATCH * D_ * D_ * 4);    // 32 MiB: k, then kvf
  bf16*  k   = (bf16*)kshare;                          // [8192,2048] bf16 (scores only)
  float* kvf = (float*)kshare;                         // [B,2048,2048] fp32 (chunk loop)
  char* sshare = take((size_t)BATCH * TC * CH * CH * 2); // 16.78 MiB: s, then kvb
  bf16* s   = (bf16*)sshare;                           // [B*TC,1024,1024] (intra only)
  bf16* kvb = (bf16*)sshare;                           // [B,2048,2048] bf16 mirror
  bf16* Wb  = (bf16*)take(W2);                         // shared weight buffer
  bf16* og = xn;

  // q and g live in d_out (64 MiB fp32 = 2 x 32 MiB bf16); overwritten by k_final
  bf16* q = (bf16*)d_out;
  bf16* g = (bf16*)d_out + (size_t)MROWS * D_;

  const int WB = (D_ * D_) / 2048;  // 2048 blocks per weight convert
  dim3 gp(D_ / 128, MROWS / 128);   // (16, 64)

  k_rms<<<MROWS, 256, 0, stream>>>(x, xn);

  k_f2b<<<WB, 256, 0, stream>>>(Wq, Wb);
  k_proj<1, 1><<<gp, 256, 0, stream>>>(xn, Wb, q, (bf16*)nullptr);
  k_f2b<<<WB, 256, 0, stream>>>(Wk, Wb);
  k_proj<1, 3><<<gp, 256, 0, stream>>>(xn, Wb, k, kT);
  k_f2b<<<WB, 256, 0, stream>>>(Wv, Wb);
  k_proj<1, 2><<<gp, 256, 0, stream>>>(xn, Wb, (bf16*)nullptr, vT);
  k_f2b<<<WB, 256, 0, stream>>>(Wg, Wb);
  k_proj<2, 1><<<gp, 256, 0, stream>>>(xn, Wb, g, (bf16*)nullptr);

  // intra-chunk: masked scores (lower-tri tiles only) then s @ v
  k_scores<<<dim3(CH / 128, CH / 128, BATCH * TC), 256, 0, stream>>>(q, k, s);
  k_ointra<<<dim3(D_ / 128, CH / 128, BATCH * TC), 256, 0, stream>>>(s, vT, og);

  // k and s are dead now; their memory becomes the KV state (fp32 + bf16)
  hipMemsetAsync(kvf, 0, (size_t)BATCH * D_ * D_ * 4, stream);
  hipMemsetAsync(kvb, 0, (size_t)BATCH * D_ * D_ * 2, stream);

  for (int t = 0; t < TC; ++t) {
    k_ointer<<<dim3(D_ / 128, CH / 128, BATCH), 256, 0, stream>>>(
        q, kvb, g, og, t, t ? D_ : 0);
    if (t < TC - 1)
      k_update<<<dim3(D_ / 128, D_ / 128, BATCH), 256, 0, stream>>>(vT, kT, kvf,
                                                                    kvb, t);
  }

  k_f2b<<<WB, 256, 0, stream>>>(Wp, Wb);
  k_final<<<dim3(D_ / 128, MROWS / 128), 256, 0, stream>>>(og, Wb, out);
}